// Round 11
// baseline (585.139 us; speedup 1.0000x reference)
//
#include <hip/hip_runtime.h>
#include <math.h>

// Problem constants (fixed by the reference)
#define B_ 4
#define T_ 2048
#define D_ 2048
#define L_ 2048
#define KW 4
#define M_ (B_*T_)       // 8192 rows for all GEMMs

typedef unsigned short u16;
typedef unsigned short u16x8 __attribute__((ext_vector_type(8)));
typedef __bf16 bf16x8 __attribute__((ext_vector_type(8)));
typedef float f32x4 __attribute__((ext_vector_type(4)));

__device__ __forceinline__ u16 f2bf(float f) {       // RNE f32 -> bf16 bits
    unsigned u = __float_as_uint(f);
    u += 0x7fffu + ((u >> 16) & 1u);
    return (u16)(u >> 16);
}
__device__ __forceinline__ float bf2f(u16 h) {
    return __uint_as_float(((unsigned)h) << 16);
}
__device__ __forceinline__ float gelu_exact(float v) {
    return 0.5f * v * (1.0f + erff(v * 0.70710678118654752440f));
}
__device__ __forceinline__ float sigmoidf_(float v) {
    return 1.0f / (1.0f + __expf(-v));
}
__device__ __forceinline__ void gload16(const void* g, void* l) {
    __builtin_amdgcn_global_load_lds(
        (const __attribute__((address_space(1))) void*)g,
        (__attribute__((address_space(3))) void*)l,
        16, 0, 0);
}
__device__ __forceinline__ void bar() {
    __builtin_amdgcn_s_barrier();
}

// ---------------- cast x -> bf16 ----------------
__global__ __launch_bounds__(256)
void castx_kernel(const float* __restrict__ in, u16* __restrict__ out)
{
    const int i = blockIdx.x * 256 + threadIdx.x;      // one float4
    float4 v = ((const float4*)in)[i];
    ushort4 o;
    o.x = f2bf(v.x); o.y = f2bf(v.y); o.z = f2bf(v.z); o.w = f2bf(v.w);
    ((ushort4*)out)[i] = o;
}

// ---------------- transpose-cast weight [K,N] f32 -> [N,K] bf16 ----------------
__global__ __launch_bounds__(256)
void transcast_kernel(const float* __restrict__ in, u16* __restrict__ out,
                      int Kd, int Nd)
{
    __shared__ float tile[32][33];
    const int bx = blockIdx.x;          // along N
    const int by = blockIdx.y;          // along K
    const int tx = threadIdx.x & 31;
    const int ty = threadIdx.x >> 5;    // 0..7
    #pragma unroll
    for (int j = 0; j < 4; ++j) {
        const int r = by*32 + ty + j*8;
        tile[ty + j*8][tx] = in[(size_t)r * Nd + bx*32 + tx];
    }
    __syncthreads();
    #pragma unroll
    for (int j = 0; j < 4; ++j) {
        const int n = bx*32 + ty + j*8;
        out[(size_t)n * Kd + by*32 + tx] = f2bf(tile[tx][ty + j*8]);
    }
}

// =====================================================================
// FUSED dual-B GEMM (round 11): C1 = epi1(A@B1^T), C2 = epi2(A@B2^T).
// Exploits shared-A structure (GEMM1/2 share x; GEMM4/5 share conv):
// stages A ONCE, runs 32 MFMA per K-iteration against the same
// staging/sync wall that r3..r10 showed is ~constant (~2000cy) per iter
// regardless of schedule -> ~1.45x effective per GEMM.
// 128x128 tile, BK=32, 4 waves, per-wave 64x64 DUAL output, 256 threads.
// LDS 72 KB: 3-slot pipeline (A|B1|B2 8KB each per slot) -> 2 blocks/CU.
// acc = 2x64 = 128 VGPR; total ~210 (under the 256 spill cliff - r9
// lesson: no fragment double-buffering at this acc size).
//
// Sync skeleton = r10's proven pattern (passed, 0 conflicts):
//   prologue: STAGE(0),STAGE(1) [6 gloads/thread each]; vmcnt(6)
//   retires t0 (BEFORE bar - cross-wave vis, r5 lesson); bar
//   iter g: ds_read slot g%3 (12 b128); STAGE(g+2) -> slot (g-1)%3
//           [reuse distance 3: its readers completed at iter g-1];
//           32 MFMA; vmcnt(6) retires t(g+1) [12 outstanding -> 6];
//           tail g=NT-2: vmcnt(0); bar
// Swizzle identical to r10 (verified SQ_LDS_BANK_CONFLICT = 0):
//   stage: pre-swizzled global slot (lane&3)^((lane>>3)&3), linear dest;
//   read: slot q^((lr>>1)&3). 8 bank-quads x 8 lanes = b128 floor.
//
// MODE 0: C1 = GELU(A@B1+b1) [y], C2 = A@B2+b2 [xb]
// MODE 1: gates + FUSED RG-LRU epilogue: g1=sig(A@B1+b1), g2=sig(A@B2+b2),
//   a = exp(-8*g2*softplus(ap)) (0 at t==0), mult = sqrt(1-a^2) (1 at t==0),
//   C1 = a, C2 = g1*conv*mult.  Kills the rglru pass (132 MB traffic).
// =====================================================================
template<int MODE>
__global__ __launch_bounds__(256)
void dgemm_kernel(const u16* __restrict__ A, const u16* __restrict__ B1T,
                  const u16* __restrict__ B2T,
                  const float* __restrict__ bias1, const float* __restrict__ bias2,
                  u16* __restrict__ C1, u16* __restrict__ C2,
                  const u16* __restrict__ convp, const float* __restrict__ ap,
                  int M, int N, int K)
{
    __shared__ __align__(16) u16 lds[36864];   // 3 x (A 4096 | B1 4096 | B2 4096) elems
    u16* ldsB1 = lds + 12288;
    u16* ldsB2 = lds + 24576;

    const int tid  = threadIdx.x;
    const int wave = tid >> 6;          // 0..3
    const int lane = tid & 63;

    // bijective XCD swizzle (nwg = 1024, %8 == 0)
    const int nbx = N >> 7;                       // N/128
    const int nwg = nbx * (M >> 7);
    const int bid = blockIdx.x;
    const int li  = (bid & 7) * (nwg >> 3) + (bid >> 3);
    const int bm  = (li / nbx) * 128;
    const int bn  = (li % nbx) * 128;

    const int wr = wave >> 1;           // 0..1 (M half: 64 rows)
    const int wn = wave & 1;            // 0..1 (N half: 64 cols)
    const int lr = lane & 15;
    const int q  = lane >> 4;

    // ---- staging: chunk = 16 rows x 64B; 8 chunks per matrix; wave w owns
    //      chunks {w, w+4} of each of A/B1/B2 -> 6 gloads/thread/K-tile.
    const int grow  = lane >> 2;                       // row within chunk
    const int gslot = (lane & 3) ^ ((lane >> 3) & 3);  // pre-swizzled k-slot
    const u16* gA0  = A   + (size_t)(bm + wave*16     + grow) * K + gslot*8;
    const u16* gA1  = A   + (size_t)(bm + (wave+4)*16 + grow) * K + gslot*8;
    const u16* gB10 = B1T + (size_t)(bn + wave*16     + grow) * K + gslot*8;
    const u16* gB11 = B1T + (size_t)(bn + (wave+4)*16 + grow) * K + gslot*8;
    const u16* gB20 = B2T + (size_t)(bn + wave*16     + grow) * K + gslot*8;
    const u16* gB21 = B2T + (size_t)(bn + (wave+4)*16 + grow) * K + gslot*8;
    const int d0 = wave*512     + lane*8;
    const int d1 = (wave+4)*512 + lane*8;

    auto STAGE = [&](int g) {
        const int s = g % 3;
        const size_t kg = (size_t)g << 5;
        u16* a  = lds   + s*4096;
        u16* b1 = ldsB1 + s*4096;
        u16* b2 = ldsB2 + s*4096;
        gload16(gA0  + kg, &a [d0]);
        gload16(gA1  + kg, &a [d1]);
        gload16(gB10 + kg, &b1[d0]);
        gload16(gB11 + kg, &b1[d1]);
        gload16(gB20 + kg, &b2[d0]);
        gload16(gB21 + kg, &b2[d1]);
    };

    // read-side swizzled k-slot (elems)
    const int ksw = (q ^ ((lr >> 1) & 3)) * 8;

    f32x4 acc1[4][4] = {};
    f32x4 acc2[4][4] = {};

    // ---- prologue ----
    STAGE(0); STAGE(1);
    asm volatile("s_waitcnt vmcnt(6)" ::: "memory");   // retire tile 0 (before bar)
    bar();

    const int NT = K >> 5;              // 64 K-tiles
    for (int g = 0; g < NT; ++g) {
        const int s = g % 3;
        const u16* Ab  = lds   + s*4096;
        const u16* B1b = ldsB1 + s*4096;
        const u16* B2b = ldsB2 + s*4096;

        bf16x8 a[4], b1[4], b2[4];
        #pragma unroll
        for (int i = 0; i < 4; ++i)
            a[i] = *(const bf16x8*)&Ab[(wr*64 + i*16 + lr)*32 + ksw];
        #pragma unroll
        for (int j = 0; j < 4; ++j) {
            b1[j] = *(const bf16x8*)&B1b[(wn*64 + j*16 + lr)*32 + ksw];
            b2[j] = *(const bf16x8*)&B2b[(wn*64 + j*16 + lr)*32 + ksw];
        }

        if (g + 2 < NT) STAGE(g + 2);   // slot (g+2)%3 == (g-1)%3: safe (ledger)

        __builtin_amdgcn_s_setprio(1);
        #pragma unroll
        for (int i = 0; i < 4; ++i)
            #pragma unroll
            for (int j = 0; j < 4; ++j) {
                acc1[i][j] = __builtin_amdgcn_mfma_f32_16x16x32_bf16(a[i], b1[j], acc1[i][j], 0, 0, 0);
                acc2[i][j] = __builtin_amdgcn_mfma_f32_16x16x32_bf16(a[i], b2[j], acc2[i][j], 0, 0, 0);
            }
        __builtin_amdgcn_s_setprio(0);

        if (g + 2 < NT)      { asm volatile("s_waitcnt vmcnt(6)" ::: "memory"); }
        else if (g + 1 < NT) { asm volatile("s_waitcnt vmcnt(0)" ::: "memory"); }
        bar();
    }

    // ---- epilogue; C/D layout: col = lane&15, row = (lane>>4)*4 + reg ----
    const int orow = (lane >> 4) * 4;
    float bv1[4], bv2[4], spv[4];
    #pragma unroll
    for (int nj = 0; nj < 4; ++nj) {
        const int col = bn + wn*64 + nj*16 + lr;
        bv1[nj] = bias1[col];
        bv2[nj] = bias2[col];
        if (MODE == 1) spv[nj] = log1pf(expf(ap[col]));   // softplus(a_param)
    }
    #pragma unroll
    for (int mi = 0; mi < 4; ++mi) {
        #pragma unroll
        for (int r = 0; r < 4; ++r) {
            const int row = bm + wr*64 + mi*16 + orow + r;
            const size_t rb = (size_t)row * N + bn + wn*64 + lr;
            const int t = row & (T_ - 1);
            #pragma unroll
            for (int nj = 0; nj < 4; ++nj) {
                const float v1 = acc1[mi][nj][r] + bv1[nj];
                const float v2 = acc2[mi][nj][r] + bv2[nj];
                if (MODE == 0) {
                    C1[rb + nj*16] = f2bf(gelu_exact(v1));   // y
                    C2[rb + nj*16] = f2bf(v2);               // xb
                } else {
                    const float g1 = sigmoidf_(v1);          // gate_x
                    const float g2 = sigmoidf_(v2);          // gate_a
                    float a    = expf(-8.0f * g2 * spv[nj]);
                    float mult = sqrtf(fmaxf(0.f, 1.0f - a*a));
                    if (t == 0) { a = 0.f; mult = 1.f; }
                    const float cv = bf2f(convp[rb + nj*16]);
                    C1[rb + nj*16] = f2bf(a);                // a
                    C2[rb + nj*16] = f2bf(g1 * cv * mult);   // nx
                }
            }
        }
    }
}

// =====================================================================
// single-B GEMM (r10 verified, unchanged): final out-projection.
// 256x128 tile, BK=32, 8 waves, per-wave 64x64, 3-slot LDS 72KB,
// 2 blocks/CU, counted vmcnt(3), zero-conflict swizzle.
// =====================================================================
__device__ __forceinline__ void store_out(float* C, size_t idx, float v) { C[idx] = v; }
__device__ __forceinline__ void store_out(u16*   C, size_t idx, float v) { C[idx] = f2bf(v); }

template<int EPI, typename OutT>   // EPI: 0 = bias only
__global__ __launch_bounds__(512, 4)
void mgemm_kernel(const u16* __restrict__ A, const u16* __restrict__ BT,
                  const float* __restrict__ bias, OutT* __restrict__ C,
                  int M, int N, int K)
{
    __shared__ __align__(16) u16 lds[36864];   // A: 3x8192 u16 | B: 3x4096 u16 = 72 KB
    u16* ldsB = lds + 24576;

    const int tid  = threadIdx.x;
    const int wave = tid >> 6;          // 0..7
    const int lane = tid & 63;

    const int nbx = N >> 7;                       // N/128
    const int nwg = nbx * (M >> 8);
    const int bid = blockIdx.x;
    const int li  = (bid & 7) * (nwg >> 3) + (bid >> 3);
    const int bm  = (li / nbx) * 256;
    const int bn  = (li % nbx) * 128;

    const int wr = wave >> 1;           // 0..3 (M quarter: 64 rows)
    const int wn = wave & 1;            // 0..1 (N half: 64 cols)
    const int lr = lane & 15;
    const int q  = lane >> 4;

    const int grow  = lane >> 2;                       // row within chunk
    const int gslot = (lane & 3) ^ ((lane >> 3) & 3);  // pre-swizzled k-slot
    const u16* gA0 = A  + (size_t)(bm + wave*16     + grow) * K + gslot*8;
    const u16* gA1 = A  + (size_t)(bm + (wave+8)*16 + grow) * K + gslot*8;
    const u16* gB0 = BT + (size_t)(bn + wave*16     + grow) * K + gslot*8;
    const int dA0 = wave*512     + lane*8;
    const int dA1 = (wave+8)*512 + lane*8;
    const int dB0 = wave*512     + lane*8;

    auto STAGE = [&](int g) {
        const int s = g % 3;
        const size_t kg = (size_t)g << 5;
        u16* a = lds  + s*8192;
        u16* b = ldsB + s*4096;
        gload16(gA0 + kg, &a[dA0]);
        gload16(gA1 + kg, &a[dA1]);
        gload16(gB0 + kg, &b[dB0]);
    };

    const int ksw = (q ^ ((lr >> 1) & 3)) * 8;

    f32x4 acc[4][4] = {};

    STAGE(0); STAGE(1);
    asm volatile("s_waitcnt vmcnt(3)" ::: "memory");
    bar();

    const int NT = K >> 5;              // 64 K-tiles
    for (int g = 0; g < NT; ++g) {
        const int s = g % 3;
        const u16* Ab = lds  + s*8192;
        const u16* Bb = ldsB + s*4096;

        bf16x8 a[4], b[4];
        #pragma unroll
        for (int i = 0; i < 4; ++i)
            a[i] = *(const bf16x8*)&Ab[(wr*64 + i*16 + lr)*32 + ksw];
        #pragma unroll
        for (int j = 0; j < 4; ++j)
            b[j] = *(const bf16x8*)&Bb[(wn*64 + j*16 + lr)*32 + ksw];

        if (g + 2 < NT) STAGE(g + 2);

        __builtin_amdgcn_s_setprio(1);
        #pragma unroll
        for (int i = 0; i < 4; ++i)
            #pragma unroll
            for (int j = 0; j < 4; ++j)
                acc[i][j] = __builtin_amdgcn_mfma_f32_16x16x32_bf16(a[i], b[j], acc[i][j], 0, 0, 0);
        __builtin_amdgcn_s_setprio(0);

        if (g + 2 < NT)      { asm volatile("s_waitcnt vmcnt(3)" ::: "memory"); }
        else if (g + 1 < NT) { asm volatile("s_waitcnt vmcnt(0)" ::: "memory"); }
        bar();
    }

    const int orow = (lane >> 4) * 4;
    float bv[4];
    #pragma unroll
    for (int nj = 0; nj < 4; ++nj) bv[nj] = bias[bn + wn*64 + nj*16 + lr];
    #pragma unroll
    for (int mi = 0; mi < 4; ++mi) {
        #pragma unroll
        for (int r = 0; r < 4; ++r) {
            const int row = bm + wr*64 + mi*16 + orow + r;
            const size_t rb = (size_t)row * N + bn + wn*64 + lr;
            #pragma unroll
            for (int nj = 0; nj < 4; ++nj) {
                float v = acc[mi][nj][r] + bv[nj];
                store_out(C, rb + nj*16, v);
            }
        }
    }
}

// ---------------- causal depthwise conv1d, width 4 (bf16 in/out) ----------------
__global__ __launch_bounds__(256)
void conv_kernel(const u16* __restrict__ xb, const float* __restrict__ cw,
                 const float* __restrict__ cb, u16* __restrict__ out)
{
    const int idx = blockIdx.x * 256 + threadIdx.x;    // one 8-elem chunk
    const int NL8 = L_ / 8;
    const int l = (idx % NL8) * 8;
    const int bt = idx / NL8;
    const int t = bt & (T_ - 1);
    float acc[8];
    #pragma unroll
    for (int j = 0; j < 8; ++j) acc[j] = cb[l + j];
    #pragma unroll
    for (int k = 0; k < KW; ++k) {
        const int ts = t - (KW-1) + k;
        if (ts >= 0) {
            u16x8 xv = *(const u16x8*)(xb + ((size_t)(bt - (KW-1-k))) * L_ + l);
            #pragma unroll
            for (int j = 0; j < 8; ++j)
                acc[j] = fmaf(cw[k*L_ + l + j], bf2f(xv[j]), acc[j]);
        }
    }
    u16x8 o;
    #pragma unroll
    for (int j = 0; j < 8; ++j) o[j] = f2bf(acc[j]);
    *(u16x8*)(out + (size_t)bt * L_ + l) = o;
}

// ---------------- chunked linear scan: h_t = a_t*h_{t-1} + x_t ----------------
#define CHUNKS 32
#define CLEN (T_ / CHUNKS)   // 64

__global__ __launch_bounds__(256)
void scan1_kernel(const u16* __restrict__ Ab, const u16* __restrict__ Xb,
                  float* __restrict__ Pb, float* __restrict__ Sb)
{
    const int l = blockIdx.x * 256 + threadIdx.x;
    const int c = blockIdx.y;
    const int b = blockIdx.z;
    size_t base = ((size_t)b * T_ + (size_t)c * CLEN) * L_ + l;
    float h = 0.f, P = 1.f;
    #pragma unroll 4
    for (int t = 0; t < CLEN; ++t) {
        float a = bf2f(Ab[base + (size_t)t * L_]);
        float x = bf2f(Xb[base + (size_t)t * L_]);
        h = fmaf(a, h, x);
        P *= a;
    }
    const size_t o = ((size_t)b * CHUNKS + c) * L_ + l;
    Pb[o] = P;
    Sb[o] = h;
}

__global__ __launch_bounds__(256)
void scan2_kernel(const float* __restrict__ Pb, const float* __restrict__ Sb,
                  float* __restrict__ Hin, float* __restrict__ hn)
{
    const int idx = blockIdx.x * 256 + threadIdx.x;  // B*L threads
    const int l = idx & (L_ - 1);
    const int b = idx >> 11;
    float h = 0.f;
    for (int c = 0; c < CHUNKS; ++c) {
        const size_t o = ((size_t)b * CHUNKS + c) * L_ + l;
        Hin[o] = h;
        h = fmaf(Pb[o], h, Sb[o]);
    }
    hn[(size_t)b * L_ + l] = h;
}

__global__ __launch_bounds__(256)
void scan3_kernel(const u16* __restrict__ Ab, const u16* __restrict__ Xb,
                  const float* __restrict__ Hin, const u16* __restrict__ Yb,
                  u16* __restrict__ Zb)
{
    const int l = blockIdx.x * 256 + threadIdx.x;
    const int c = blockIdx.y;
    const int b = blockIdx.z;
    float h = Hin[((size_t)b * CHUNKS + c) * L_ + l];
    size_t base = ((size_t)b * T_ + (size_t)c * CLEN) * L_ + l;
    #pragma unroll 4
    for (int t = 0; t < CLEN; ++t) {
        const size_t o = base + (size_t)t * L_;
        h = fmaf(bf2f(Ab[o]), h, bf2f(Xb[o]));
        Zb[o] = f2bf(h * bf2f(Yb[o]));
    }
}

// ---------------- launch ----------------
extern "C" void kernel_launch(void* const* d_in, const int* in_sizes, int n_in,
                              void* d_out, int out_size, void* d_ws, size_t ws_size,
                              hipStream_t stream)
{
    const float* x     = (const float*)d_in[0];
    const float* w_y   = (const float*)d_in[1];
    const float* b_y   = (const float*)d_in[2];
    const float* w_x   = (const float*)d_in[3];
    const float* b_x   = (const float*)d_in[4];
    const float* cw    = (const float*)d_in[5];
    const float* cb    = (const float*)d_in[6];
    const float* ap    = (const float*)d_in[7];
    const float* w_ig  = (const float*)d_in[8];
    const float* b_ig  = (const float*)d_in[9];
    const float* w_ag  = (const float*)d_in[10];
    const float* b_ag  = (const float*)d_in[11];
    const float* w_out = (const float*)d_in[12];
    const float* b_out = (const float*)d_in[13];

    float* out = (float*)d_out;               // [B,T,D] flat
    float* hn  = out + (size_t)M_ * D_;       // [B,L] appended

    // workspace layout (liveness-aliased, peak 192 MB)
    const size_t MB = 1u << 20;
    char* w = (char*)d_ws;
    u16*  xbf   = (u16*)(w + 0);        // [M,D] bf16 — dead after dgemm<0>
    u16*  wigb  = (u16*)(w + 0);        // [L,L]T bf16 — after xbf dead
    u16*  wagb  = (u16*)(w + 8*MB);
    u16*  zb    = (u16*)(w + 0);        // [M,L] bf16 — after dgemm<1>
    u16*  ybf   = (u16*)(w + 32*MB);    // [M,L] bf16
    u16*  xbbf  = (u16*)(w + 64*MB);    // [M,L] bf16 — dead after conv
    u16*  woutb = (u16*)(w + 64*MB);    // after xbbf dead
    float* Pb   = (float*)(w + 72*MB);
    float* Sb   = (float*)(w + 73*MB);
    float* Hin  = (float*)(w + 74*MB);
    u16*  wyb   = (u16*)(w + 96*MB);    // weights dead after dgemm<0>
    u16*  wxb   = (u16*)(w + 104*MB);
    u16*  convb = (u16*)(w + 96*MB);    // [M,L] bf16 — after wyb/wxb dead
    u16*  gx    = (u16*)(w + 128*MB);   // a   (written directly by dgemm<1>)
    u16*  ga    = (u16*)(w + 160*MB);   // nx

    const dim3 blk(256);
    const dim3 blkG(512);
    const dim3 gD((L_/128) * (M_/128));             // 1024 blocks (dual GEMM)
    const dim3 gG((L_/128) * (M_/256));             // 512 blocks (single GEMM)
    const dim3 gT(2048/32, 2048/32);                // transpose grids
    const int  gE8 = (M_ * L_ / 8) / 256;           // 8-wide elementwise
    const dim3 gScan(L_/256, CHUNKS, B_);

    // casts for stage 1
    hipLaunchKernelGGL(castx_kernel, dim3((M_*D_/4)/256), blk, 0, stream, x, xbf);
    hipLaunchKernelGGL(transcast_kernel, gT, blk, 0, stream, w_y, wyb, D_, L_);
    hipLaunchKernelGGL(transcast_kernel, gT, blk, 0, stream, w_x, wxb, D_, L_);
    // 1+2 fused: y = GELU(x@w_y+b_y) -> ybf ; xb = x@w_x+b_x -> xbbf
    hipLaunchKernelGGL((dgemm_kernel<0>), gD, blk, 0, stream,
                       xbf, wyb, wxb, b_y, b_x, ybf, xbbf,
                       (const u16*)nullptr, (const float*)nullptr, M_, L_, D_);
    // casts for stage 2 (xbf region now dead)
    hipLaunchKernelGGL(transcast_kernel, gT, blk, 0, stream, w_ig, wigb, L_, L_);
    hipLaunchKernelGGL(transcast_kernel, gT, blk, 0, stream, w_ag, wagb, L_, L_);
    // 3. conv(xbbf) -> convb (wyb/wxb region dead)
    hipLaunchKernelGGL(conv_kernel, dim3(gE8), blk, 0, stream, xbbf, cw, cb, convb);
    hipLaunchKernelGGL(transcast_kernel, gT, blk, 0, stream, w_out, woutb, L_, D_);  // xbbf dead
    // 4+5+6 fused: gates + RG-LRU pointwise -> a (gx buf), nx (ga buf)
    hipLaunchKernelGGL((dgemm_kernel<1>), gD, blk, 0, stream,
                       convb, wigb, wagb, b_ig, b_ag, gx, ga, convb, ap, M_, L_, L_);
    // 7-9. chunked scan; pass 3 fuses z = h*y -> zb (wig/wag region dead)
    hipLaunchKernelGGL(scan1_kernel, gScan, blk, 0, stream, gx, ga, Pb, Sb);
    hipLaunchKernelGGL(scan2_kernel, dim3(B_*L_/256), blk, 0, stream, Pb, Sb, Hin, hn);
    hipLaunchKernelGGL(scan3_kernel, gScan, blk, 0, stream, gx, ga, Hin, ybf, zb);
    // 10. out = z @ w_out + b_out -> d_out (f32)
    hipLaunchKernelGGL((mgemm_kernel<0, float>), gG, blkG, 0, stream, zb, woutb, b_out, out, M_, D_, L_);
}

// Round 12
// 523.227 us; speedup vs baseline: 1.1183x; 1.1183x over previous
//
#include <hip/hip_runtime.h>
#include <math.h>

// Problem constants (fixed by the reference)
#define B_ 4
#define T_ 2048
#define D_ 2048
#define L_ 2048
#define KW 4
#define M_ (B_*T_)       // 8192 rows for all GEMMs

typedef unsigned short u16;
typedef unsigned short u16x8 __attribute__((ext_vector_type(8)));
typedef __bf16 bf16x8 __attribute__((ext_vector_type(8)));
typedef float f32x4 __attribute__((ext_vector_type(4)));

__device__ __forceinline__ u16 f2bf(float f) {       // RNE f32 -> bf16 bits
    unsigned u = __float_as_uint(f);
    u += 0x7fffu + ((u >> 16) & 1u);
    return (u16)(u >> 16);
}
__device__ __forceinline__ float bf2f(u16 h) {
    return __uint_as_float(((unsigned)h) << 16);
}
__device__ __forceinline__ float gelu_exact(float v) {
    return 0.5f * v * (1.0f + erff(v * 0.70710678118654752440f));
}
__device__ __forceinline__ float sigmoidf_(float v) {
    return 1.0f / (1.0f + __expf(-v));
}
__device__ __forceinline__ void gload16(const void* g, void* l) {
    __builtin_amdgcn_global_load_lds(
        (const __attribute__((address_space(1))) void*)g,
        (__attribute__((address_space(3))) void*)l,
        16, 0, 0);
}
__device__ __forceinline__ void bar() {
    __builtin_amdgcn_s_barrier();
}

// ---------------- cast x -> bf16 ----------------
__global__ __launch_bounds__(256)
void castx_kernel(const float* __restrict__ in, u16* __restrict__ out)
{
    const int i = blockIdx.x * 256 + threadIdx.x;      // one float4
    float4 v = ((const float4*)in)[i];
    ushort4 o;
    o.x = f2bf(v.x); o.y = f2bf(v.y); o.z = f2bf(v.z); o.w = f2bf(v.w);
    ((ushort4*)out)[i] = o;
}

// ---------------- transpose-cast weight [K,N] f32 -> [N,K] bf16 ----------------
__global__ __launch_bounds__(256)
void transcast_kernel(const float* __restrict__ in, u16* __restrict__ out,
                      int Kd, int Nd)
{
    __shared__ float tile[32][33];
    const int bx = blockIdx.x;          // along N
    const int by = blockIdx.y;          // along K
    const int tx = threadIdx.x & 31;
    const int ty = threadIdx.x >> 5;    // 0..7
    #pragma unroll
    for (int j = 0; j < 4; ++j) {
        const int r = by*32 + ty + j*8;
        tile[ty + j*8][tx] = in[(size_t)r * Nd + bx*32 + tx];
    }
    __syncthreads();
    #pragma unroll
    for (int j = 0; j < 4; ++j) {
        const int n = bx*32 + ty + j*8;
        out[(size_t)n * Kd + by*32 + tx] = f2bf(tile[tx][ty + j*8]);
    }
}

// =====================================================================
// bf16 MFMA GEMM — r10-verified structure (fastest measured dispatch:
// 86.4us, MfmaUtil 34%, 0 conflicts), with RG-LRU fused as epilogues.
// C[M,N] = epi(A[M,K] @ BT[N,K]^T + bias)
// 256x128 tile, BK=32, 8 waves (4M x 2N), per-wave 64x64, 512 threads.
// LDS 72 KB 3-slot pipeline -> 2 blocks/CU; __launch_bounds__(512,4).
// Sync skeleton (r10 proven): prologue STAGE(0),STAGE(1); vmcnt(3)
// retires t0 BEFORE bar (cross-wave vis, r5 lesson); iter g: ds_read
// slot g%3 (8 b128) | STAGE(g+2) -> slot (g-1)%3 (reuse distance 3) |
// 16 MFMA | vmcnt(3) (tail: vmcnt(0)) | bar.
// Swizzle (verified 0 conflicts): stage pre-swizzled global slot
// (lane&3)^((lane>>3)&3) with linear LDS dest (rule 21); read slot
// q^((lr>>1)&3) -> 8 bank-quads x 8 lanes = b128 floor.
//
// EPI: 0 = bias (OutT=float or u16), 1 = gelu,
//      3 = RG-LRU "a":  g2=sig(v); a = (t==0)?0:exp(-8*g2*softplus(ap[col]))
//      4 = RG-LRU "nx": gx=sig(v); a=auxA[idx]; cv=auxC[idx];
//                       nx = gx*cv*sqrt(1-a^2)   (t==0: a==0 -> mult=1)
// r11 lesson recorded: dual-B fusion quadruples panel fetch (292MB) and
// thrashes L2 -> slower. Shared-A is better exploited via L2, not fusion.
// =====================================================================
__device__ __forceinline__ void store_out(float* C, size_t idx, float v) { C[idx] = v; }
__device__ __forceinline__ void store_out(u16*   C, size_t idx, float v) { C[idx] = f2bf(v); }

template<int EPI, typename OutT>
__global__ __launch_bounds__(512, 4)
void mgemm_kernel(const u16* __restrict__ A, const u16* __restrict__ BT,
                  const float* __restrict__ bias, OutT* __restrict__ C,
                  int M, int N, int K,
                  const u16* __restrict__ auxA,   // EPI=4: a buffer
                  const u16* __restrict__ auxC,   // EPI=4: conv buffer
                  const float* __restrict__ ap)   // EPI=3: a_param
{
    __shared__ __align__(16) u16 lds[36864];   // A: 3x8192 u16 | B: 3x4096 u16 = 72 KB
    u16* ldsB = lds + 24576;

    const int tid  = threadIdx.x;
    const int wave = tid >> 6;          // 0..7
    const int lane = tid & 63;

    // bijective XCD swizzle (nwg = 512, %8 == 0)
    const int nbx = N >> 7;                       // N/128
    const int nwg = nbx * (M >> 8);
    const int bid = blockIdx.x;
    const int li  = (bid & 7) * (nwg >> 3) + (bid >> 3);
    const int bm  = (li / nbx) * 256;
    const int bn  = (li % nbx) * 128;

    const int wr = wave >> 1;           // 0..3 (M quarter: 64 rows)
    const int wn = wave & 1;            // 0..1 (N half: 64 cols)
    const int lr = lane & 15;
    const int q  = lane >> 4;

    const int grow  = lane >> 2;                       // row within chunk
    const int gslot = (lane & 3) ^ ((lane >> 3) & 3);  // pre-swizzled k-slot
    const u16* gA0 = A  + (size_t)(bm + wave*16     + grow) * K + gslot*8;
    const u16* gA1 = A  + (size_t)(bm + (wave+8)*16 + grow) * K + gslot*8;
    const u16* gB0 = BT + (size_t)(bn + wave*16     + grow) * K + gslot*8;
    const int dA0 = wave*512     + lane*8;
    const int dA1 = (wave+8)*512 + lane*8;
    const int dB0 = wave*512     + lane*8;

    auto STAGE = [&](int g) {
        const int s = g % 3;
        const size_t kg = (size_t)g << 5;
        u16* a = lds  + s*8192;
        u16* b = ldsB + s*4096;
        gload16(gA0 + kg, &a[dA0]);
        gload16(gA1 + kg, &a[dA1]);
        gload16(gB0 + kg, &b[dB0]);
    };

    const int ksw = (q ^ ((lr >> 1) & 3)) * 8;   // read-side swizzled k-slot

    f32x4 acc[4][4] = {};

    STAGE(0); STAGE(1);
    asm volatile("s_waitcnt vmcnt(3)" ::: "memory");   // retire tile 0 (before bar)
    bar();

    const int NT = K >> 5;              // 64 K-tiles
    for (int g = 0; g < NT; ++g) {
        const int s = g % 3;
        const u16* Ab = lds  + s*8192;
        const u16* Bb = ldsB + s*4096;

        bf16x8 a[4], b[4];
        #pragma unroll
        for (int i = 0; i < 4; ++i)
            a[i] = *(const bf16x8*)&Ab[(wr*64 + i*16 + lr)*32 + ksw];
        #pragma unroll
        for (int j = 0; j < 4; ++j)
            b[j] = *(const bf16x8*)&Bb[(wn*64 + j*16 + lr)*32 + ksw];

        if (g + 2 < NT) STAGE(g + 2);   // slot (g+2)%3 == (g-1)%3: safe (ledger)

        __builtin_amdgcn_s_setprio(1);
        #pragma unroll
        for (int i = 0; i < 4; ++i)
            #pragma unroll
            for (int j = 0; j < 4; ++j)
                acc[i][j] = __builtin_amdgcn_mfma_f32_16x16x32_bf16(a[i], b[j], acc[i][j], 0, 0, 0);
        __builtin_amdgcn_s_setprio(0);

        if (g + 2 < NT)      { asm volatile("s_waitcnt vmcnt(3)" ::: "memory"); }
        else if (g + 1 < NT) { asm volatile("s_waitcnt vmcnt(0)" ::: "memory"); }
        bar();
    }

    // ---- epilogue; C/D layout: col = lane&15, row = (lane>>4)*4 + reg ----
    const int orow = (lane >> 4) * 4;
    float bv[4], spv[4];
    #pragma unroll
    for (int nj = 0; nj < 4; ++nj) {
        const int col = bn + wn*64 + nj*16 + lr;
        bv[nj] = bias[col];
        if (EPI == 3) spv[nj] = log1pf(expf(ap[col]));   // softplus(a_param)
    }
    #pragma unroll
    for (int mi = 0; mi < 4; ++mi) {
        #pragma unroll
        for (int r = 0; r < 4; ++r) {
            const int row = bm + wr*64 + mi*16 + orow + r;
            const size_t rb = (size_t)row * N + bn + wn*64 + lr;
            const int t = row & (T_ - 1);
            #pragma unroll
            for (int nj = 0; nj < 4; ++nj) {
                float v = acc[mi][nj][r] + bv[nj];
                if (EPI == 1) {
                    v = gelu_exact(v);
                } else if (EPI == 3) {
                    const float g2 = sigmoidf_(v);
                    v = (t == 0) ? 0.f : expf(-8.0f * g2 * spv[nj]);
                } else if (EPI == 4) {
                    const float gx = sigmoidf_(v);
                    const float av = bf2f(auxA[rb + nj*16]);
                    const float cv = bf2f(auxC[rb + nj*16]);
                    v = gx * cv * sqrtf(fmaxf(0.f, 1.0f - av*av));
                }
                store_out(C, rb + nj*16, v);
            }
        }
    }
}

// ---------------- causal depthwise conv1d, width 4 (bf16 in/out) ----------------
__global__ __launch_bounds__(256)
void conv_kernel(const u16* __restrict__ xb, const float* __restrict__ cw,
                 const float* __restrict__ cb, u16* __restrict__ out)
{
    const int idx = blockIdx.x * 256 + threadIdx.x;    // one 8-elem chunk
    const int NL8 = L_ / 8;
    const int l = (idx % NL8) * 8;
    const int bt = idx / NL8;
    const int t = bt & (T_ - 1);
    float acc[8];
    #pragma unroll
    for (int j = 0; j < 8; ++j) acc[j] = cb[l + j];
    #pragma unroll
    for (int k = 0; k < KW; ++k) {
        const int ts = t - (KW-1) + k;
        if (ts >= 0) {
            u16x8 xv = *(const u16x8*)(xb + ((size_t)(bt - (KW-1-k))) * L_ + l);
            #pragma unroll
            for (int j = 0; j < 8; ++j)
                acc[j] = fmaf(cw[k*L_ + l + j], bf2f(xv[j]), acc[j]);
        }
    }
    u16x8 o;
    #pragma unroll
    for (int j = 0; j < 8; ++j) o[j] = f2bf(acc[j]);
    *(u16x8*)(out + (size_t)bt * L_ + l) = o;
}

// ---------------- chunked linear scan: h_t = a_t*h_{t-1} + x_t ----------------
#define CHUNKS 32
#define CLEN (T_ / CHUNKS)   // 64

__global__ __launch_bounds__(256)
void scan1_kernel(const u16* __restrict__ Ab, const u16* __restrict__ Xb,
                  float* __restrict__ Pb, float* __restrict__ Sb)
{
    const int l = blockIdx.x * 256 + threadIdx.x;
    const int c = blockIdx.y;
    const int b = blockIdx.z;
    size_t base = ((size_t)b * T_ + (size_t)c * CLEN) * L_ + l;
    float h = 0.f, P = 1.f;
    #pragma unroll 4
    for (int t = 0; t < CLEN; ++t) {
        float a = bf2f(Ab[base + (size_t)t * L_]);
        float x = bf2f(Xb[base + (size_t)t * L_]);
        h = fmaf(a, h, x);
        P *= a;
    }
    const size_t o = ((size_t)b * CHUNKS + c) * L_ + l;
    Pb[o] = P;
    Sb[o] = h;
}

__global__ __launch_bounds__(256)
void scan2_kernel(const float* __restrict__ Pb, const float* __restrict__ Sb,
                  float* __restrict__ Hin, float* __restrict__ hn)
{
    const int idx = blockIdx.x * 256 + threadIdx.x;  // B*L threads
    const int l = idx & (L_ - 1);
    const int b = idx >> 11;
    float h = 0.f;
    for (int c = 0; c < CHUNKS; ++c) {
        const size_t o = ((size_t)b * CHUNKS + c) * L_ + l;
        Hin[o] = h;
        h = fmaf(Pb[o], h, Sb[o]);
    }
    hn[(size_t)b * L_ + l] = h;
}

__global__ __launch_bounds__(256)
void scan3_kernel(const u16* __restrict__ Ab, const u16* __restrict__ Xb,
                  const float* __restrict__ Hin, const u16* __restrict__ Yb,
                  u16* __restrict__ Zb)
{
    const int l = blockIdx.x * 256 + threadIdx.x;
    const int c = blockIdx.y;
    const int b = blockIdx.z;
    float h = Hin[((size_t)b * CHUNKS + c) * L_ + l];
    size_t base = ((size_t)b * T_ + (size_t)c * CLEN) * L_ + l;
    #pragma unroll 4
    for (int t = 0; t < CLEN; ++t) {
        const size_t o = base + (size_t)t * L_;
        h = fmaf(bf2f(Ab[o]), h, bf2f(Xb[o]));
        Zb[o] = f2bf(h * bf2f(Yb[o]));
    }
}

// ---------------- launch ----------------
extern "C" void kernel_launch(void* const* d_in, const int* in_sizes, int n_in,
                              void* d_out, int out_size, void* d_ws, size_t ws_size,
                              hipStream_t stream)
{
    const float* x     = (const float*)d_in[0];
    const float* w_y   = (const float*)d_in[1];
    const float* b_y   = (const float*)d_in[2];
    const float* w_x   = (const float*)d_in[3];
    const float* b_x   = (const float*)d_in[4];
    const float* cw    = (const float*)d_in[5];
    const float* cb    = (const float*)d_in[6];
    const float* ap    = (const float*)d_in[7];
    const float* w_ig  = (const float*)d_in[8];
    const float* b_ig  = (const float*)d_in[9];
    const float* w_ag  = (const float*)d_in[10];
    const float* b_ag  = (const float*)d_in[11];
    const float* w_out = (const float*)d_in[12];
    const float* b_out = (const float*)d_in[13];

    float* out = (float*)d_out;               // [B,T,D] flat
    float* hn  = out + (size_t)M_ * D_;       // [B,L] appended

    // workspace layout (liveness-aliased, peak 192 MB)
    const size_t MB = 1u << 20;
    char* w = (char*)d_ws;
    u16*  xbf   = (u16*)(w + 0);        // [M,D] bf16 — dead after GEMM2
    u16*  wigb  = (u16*)(w + 0);        // [L,L]T bf16 — after xbf dead
    u16*  wagb  = (u16*)(w + 8*MB);
    u16*  zb    = (u16*)(w + 0);        // [M,L] bf16 — after gates
    u16*  ybf   = (u16*)(w + 32*MB);    // [M,L] bf16
    u16*  xbbf  = (u16*)(w + 64*MB);    // [M,L] bf16 — dead after conv
    u16*  woutb = (u16*)(w + 64*MB);    // after xbbf dead
    float* Pb   = (float*)(w + 72*MB);
    float* Sb   = (float*)(w + 73*MB);
    float* Hin  = (float*)(w + 74*MB);
    u16*  wyb   = (u16*)(w + 96*MB);    // weights dead after GEMM2
    u16*  wxb   = (u16*)(w + 104*MB);
    u16*  convb = (u16*)(w + 96*MB);    // [M,L] bf16 — after wyb/wxb dead
    u16*  abuf  = (u16*)(w + 128*MB);   // a   (written by GEMM_ag epilogue)
    u16*  nxbuf = (u16*)(w + 160*MB);   // nx  (written by GEMM_ig epilogue)

    const dim3 blk(256);
    const dim3 blkG(512);
    const dim3 gG((L_/128) * (M_/256));             // 512 blocks -> 2/CU resident
    const dim3 gT(2048/32, 2048/32);                // transpose grids
    const int  gE8 = (M_ * L_ / 8) / 256;           // 8-wide elementwise
    const dim3 gScan(L_/256, CHUNKS, B_);
    const u16* nu = nullptr;

    // casts for stage 1
    hipLaunchKernelGGL(castx_kernel, dim3((M_*D_/4)/256), blk, 0, stream, x, xbf);
    hipLaunchKernelGGL(transcast_kernel, gT, blk, 0, stream, w_y, wyb, D_, L_);
    hipLaunchKernelGGL(transcast_kernel, gT, blk, 0, stream, w_x, wxb, D_, L_);
    // 1. y = GELU(x@w_y + b_y) -> ybf
    hipLaunchKernelGGL((mgemm_kernel<1, u16>), gG, blkG, 0, stream,
                       xbf, wyb, b_y, ybf, M_, L_, D_, nu, nu, (const float*)nullptr);
    // 2. xb = x@w_x + b_x -> xbbf
    hipLaunchKernelGGL((mgemm_kernel<0, u16>), gG, blkG, 0, stream,
                       xbf, wxb, b_x, xbbf, M_, L_, D_, nu, nu, (const float*)nullptr);
    // casts for stage 2 (xbf region now dead)
    hipLaunchKernelGGL(transcast_kernel, gT, blk, 0, stream, w_ig, wigb, L_, L_);
    hipLaunchKernelGGL(transcast_kernel, gT, blk, 0, stream, w_ag, wagb, L_, L_);
    // 3. conv(xbbf) -> convb (wyb/wxb region dead)
    hipLaunchKernelGGL(conv_kernel, dim3(gE8), blk, 0, stream, xbbf, cw, cb, convb);
    hipLaunchKernelGGL(transcast_kernel, gT, blk, 0, stream, w_out, woutb, L_, D_);  // xbbf dead
    // 4. gate_a GEMM + fused a-epilogue -> abuf
    hipLaunchKernelGGL((mgemm_kernel<3, u16>), gG, blkG, 0, stream,
                       convb, wagb, b_ag, abuf, M_, L_, L_, nu, nu, ap);
    // 5. gate_x GEMM + fused nx-epilogue (reads abuf, convb) -> nxbuf
    hipLaunchKernelGGL((mgemm_kernel<4, u16>), gG, blkG, 0, stream,
                       convb, wigb, b_ig, nxbuf, M_, L_, L_, abuf, convb, (const float*)nullptr);
    // 6-8. chunked scan; pass 3 fuses z = h*y -> zb (wig/wag region dead)
    hipLaunchKernelGGL(scan1_kernel, gScan, blk, 0, stream, abuf, nxbuf, Pb, Sb);
    hipLaunchKernelGGL(scan2_kernel, dim3(B_*L_/256), blk, 0, stream, Pb, Sb, Hin, hn);
    hipLaunchKernelGGL(scan3_kernel, gScan, blk, 0, stream, abuf, nxbuf, Hin, ybf, zb);
    // 9. out = z @ w_out + b_out -> d_out (f32)
    hipLaunchKernelGGL((mgemm_kernel<0, float>), gG, blkG, 0, stream,
                       zb, woutb, b_out, out, M_, D_, L_, nu, nu, (const float*)nullptr);
}